// Round 8
// baseline (164.963 us; speedup 1.0000x reference)
//
#include <hip/hip_runtime.h>
#include <math.h>

#define DDIM 4096
#define NEXP 64

typedef short s16x8 __attribute__((ext_vector_type(8)));
typedef float f32x4 __attribute__((ext_vector_type(4)));
typedef float f32x4v __attribute__((ext_vector_type(4)));

__device__ __forceinline__ unsigned cvt_pk_bf16(float a, float b) {
  unsigned r;
  asm("v_cvt_pk_bf16_f32 %0, %1, %2" : "=v"(r) : "v"(a), "v"(b));
  return r;  // lo16 = bf16(a), hi16 = bf16(b)
}

// 3-way bf16 split of two floats -> packed hi/mid/lo words
__device__ __forceinline__ void split2(float a, float b, unsigned& H,
                                       unsigned& M, unsigned& L) {
  H = cvt_pk_bf16(a, b);
  float h0 = __uint_as_float(H << 16);
  float h1 = __uint_as_float(H & 0xffff0000u);
  float r0 = a - h0, r1 = b - h1;
  M = cvt_pk_bf16(r0, r1);
  float m0 = __uint_as_float(M << 16);
  float m1 = __uint_as_float(M & 0xffff0000u);
  L = cvt_pk_bf16(r0 - m0, r1 - m1);
}

union U8 { unsigned u[4]; s16x8 v; };
__device__ __forceinline__ s16x8 pack8(const unsigned* a) {
  U8 t;
  t.u[0] = a[0]; t.u[1] = a[1]; t.u[2] = a[2]; t.u[3] = a[3];
  return t.v;
}

#define MFMA(A, B, C) __builtin_amdgcn_mfma_f32_16x16x32_bf16(A, B, C, 0, 0, 0)

// prefetch 6 w-fragments (c = C0..C0+5) of k-tile KB into register bank WB
#define HALFW(WB, C0, KB)                                                      \
  {                                                                            \
    const ushort* wkp = wfg + (size_t)(KB) * (12 * 512) + (C0) * 512 + lane * 8; \
    _Pragma("unroll") for (int c = 0; c < 6; ++c)                              \
        WB[c] = *(const s16x8*)(wkp + c * 512);                                \
  }

// 6-product split-bf16 MFMA group for one expert-group
#define MEG(EG, WH, WM, WL)                                                    \
  accH[EG] = MFMA(ah, WH, accH[EG]);                                           \
  accC[EG] = MFMA(ah, WM, accC[EG]);                                           \
  accC[EG] = MFMA(am, WH, accC[EG]);                                           \
  accC[EG] = MFMA(am, WM, accC[EG]);                                           \
  accC[EG] = MFMA(ah, WL, accC[EG]);                                           \
  accC[EG] = MFMA(al, WH, accC[EG]);

// 16 free-running waves; wave (g = wv>>2, sw = wv&3): 16 tokens x 64 experts
// x k-quarter g, private acc; one __syncthreads after the sweep.
// x: NON-TEMPORAL per-lane loads (zero reuse -> keep L2 for w), 2-deep.
// w: fragment blob, L2-resident (x streams past), software-pipelined into
//    two 6-frag register banks, each issued ~1/2 KSTEP before consumption.
__global__ __launch_bounds__(1024) void moe_gate_main(
    const float* __restrict__ x,    // [N][4096]
    const ushort* __restrict__ wf,  // [128kb][4eg][3lvl][64lane][8] bf16 bits
    float* __restrict__ out,        // idx [N*8], w [N*8], aux
    float* __restrict__ pi_g, float* __restrict__ ce_g, int N) {
  __shared__ float smem[17536];  // 70 KB: 4x4352 partials + inv_s + ce
  float* lt = smem;              // final logits [64 e][stride 68]
  float* inv_s = smem + 17408;
  float* ce_lds = smem + 17472;

  const int tid = threadIdx.x;
  const int lane = tid & 63;
  const int wv = tid >> 6;   // 0..15
  const int g = wv >> 2;     // k-quarter
  const int sw = wv & 3;     // token sub-group
  const int tok0 = blockIdx.x << 6;
  const int rot = ((blockIdx.x * 9) + (g << 3)) & 31;

  const float* xr = x + (size_t)(tok0 + (sw << 4) + (lane & 15)) * DDIM +
                    (g << 10) + ((lane >> 4) << 3);
  const ushort* wfg = wf + (size_t)g * 32 * 12 * 512;

  f32x4 accH[4], accC[4];
#pragma unroll
  for (int eg = 0; eg < 4; ++eg) {
#pragma unroll
    for (int r = 0; r < 4; ++r) { accH[eg][r] = 0.f; accC[eg][r] = 0.f; }
  }

  s16x8 wEvn[6], wOdd[6];  // eg0,1 / eg2,3 fragment banks (static idx only)

  // prologue: w bank for (kb=rot, eg0,1); x 2-deep non-temporal
  HALFW(wEvn, 0, rot);
  const int p1 = (rot + 1) & 31;
  f32x4v x0a = __builtin_nontemporal_load((const f32x4v*)(xr + rot * 32));
  f32x4v x0b = __builtin_nontemporal_load((const f32x4v*)(xr + rot * 32) + 1);
  f32x4v x1a = __builtin_nontemporal_load((const f32x4v*)(xr + p1 * 32));
  f32x4v x1b = __builtin_nontemporal_load((const f32x4v*)(xr + p1 * 32) + 1);

#define KSTEP(XA, XB, I)                                                       \
  {                                                                            \
    const int kbc = ((I) + rot) & 31;                                          \
    HALFW(wOdd, 6, kbc); /* eg2,3 of current kb, consumed ~400cyc later */     \
    unsigned AH[4], AM[4], AL[4];                                              \
    split2(XA[0], XA[1], AH[0], AM[0], AL[0]);                                 \
    split2(XA[2], XA[3], AH[1], AM[1], AL[1]);                                 \
    split2(XB[0], XB[1], AH[2], AM[2], AL[2]);                                 \
    split2(XB[2], XB[3], AH[3], AM[3], AL[3]);                                 \
    const s16x8 ah = pack8(AH), am = pack8(AM), al = pack8(AL);                \
    {                                                                          \
      const int kn = ((I) + 2 + rot) & 31; /* 2-deep x refill */               \
      XA = __builtin_nontemporal_load((const f32x4v*)(xr + kn * 32));          \
      XB = __builtin_nontemporal_load((const f32x4v*)(xr + kn * 32) + 1);      \
    }                                                                          \
    MEG(0, wEvn[0], wEvn[1], wEvn[2]);                                         \
    MEG(1, wEvn[3], wEvn[4], wEvn[5]);                                         \
    {                                                                          \
      const int kbn = ((I) + 1 + rot) & 31;                                    \
      HALFW(wEvn, 0, kbn); /* eg0,1 of NEXT kb */                              \
    }                                                                          \
    MEG(2, wOdd[0], wOdd[1], wOdd[2]);                                         \
    MEG(3, wOdd[3], wOdd[4], wOdd[5]);                                         \
  }

#pragma unroll 1
  for (int i = 0; i < 32; i += 2) {
    KSTEP(x0a, x0b, i);
    KSTEP(x1a, x1b, i + 1);
  }

  // per-group partial logits -> smem[g][expert*68 + token]
  {
    float* ltp = smem + g * 4352;
#pragma unroll
    for (int eg = 0; eg < 4; ++eg) {
#pragma unroll
      for (int r = 0; r < 4; ++r) {
        ltp[(eg * 16 + (lane & 15)) * 68 + (sw << 4) + ((lane >> 4) << 2) + r] =
            accH[eg][r] + accC[eg][r];
      }
    }
  }
  __syncthreads();

  // combine 4 k-partials, unscale by 1/64 (w pre-scaled x64)
  for (int idx = tid; idx < 4352; idx += 1024)
    lt[idx] = (lt[idx] + smem[4352 + idx] + smem[8704 + idx] + smem[13056 + idx]) * 0.015625f;
  __syncthreads();

  // softmax per token (store p = exp(l-m) back)
  if (tid < 64) {
    const int t = tid;
    ce_lds[t] = 0.f;
    float m = -1e30f;
#pragma unroll 1
    for (int e = 0; e < 64; ++e) m = fmaxf(m, lt[e * 68 + t]);
    float ssum = 0.f;
#pragma unroll 1
    for (int e = 0; e < 64; ++e) {
      float p = expf(lt[e * 68 + t] - m);
      lt[e * 68 + t] = p;
      ssum += p;
    }
    inv_s[t] = 1.f / ssum;
  }
  __syncthreads();

  // pi partial: per-expert sum of scores
  if (tid < 64) {
    const int e = tid;
    float ssum = 0.f;
#pragma unroll 1
    for (int t = 0; t < 64; ++t) ssum += lt[e * 68 + t] * inv_s[t];
    atomicAdd(pi_g + e, ssum);
  }
  __syncthreads();

  // stable top-8 (strict > keeps lowest index on ties; descending)
  if (tid < 64) {
    const int t = tid;
    const float invv = inv_s[t];
    const size_t tg2 = (size_t)(tok0 + t);
#pragma unroll 1
    for (int r = 0; r < 8; ++r) {
      float bv = -1.f;
      int bi = 0;
#pragma unroll 1
      for (int e = 0; e < 64; ++e) {
        float p = lt[e * 68 + t];
        if (p > bv) { bv = p; bi = e; }
      }
      lt[bi * 68 + t] = -1.f;
      atomicAdd(ce_lds + bi, 1.f);
      out[tg2 * 8 + r] = (float)bi;
      out[(size_t)N * 8 + tg2 * 8 + r] = bv * invv;
    }
  }
  __syncthreads();
  if (tid < 64) atomicAdd(ce_g + tid, ce_lds[tid]);
}

// w [64][4096] -> fragment-ordered 3-way split blob, scaled by 64
__global__ void build_wfrag(const float* __restrict__ w, ushort* __restrict__ wf) {
  const int kb = blockIdx.x;  // 0..127
  const int t = threadIdx.x;  // 256
  const int eg = t >> 6, lane = t & 63;
  const int e = (eg << 4) + (lane & 15);
  const int k0 = (kb << 5) + ((lane >> 4) << 3);
  const float* src = w + (size_t)e * DDIM + k0;
  unsigned H[4], M[4], L[4];
#pragma unroll
  for (int i = 0; i < 4; ++i) {
    float a = src[2 * i] * 64.f, b = src[2 * i + 1] * 64.f;
    split2(a, b, H[i], M[i], L[i]);
  }
  const size_t base = ((size_t)kb * 12 + eg * 3) * 512 + (size_t)lane * 8;
  *(uint4*)(wf + base) = make_uint4(H[0], H[1], H[2], H[3]);
  *(uint4*)(wf + base + 512) = make_uint4(M[0], M[1], M[2], M[3]);
  *(uint4*)(wf + base + 1024) = make_uint4(L[0], L[1], L[2], L[3]);
}

__global__ void aux_final(const float* __restrict__ pi_g,
                          const float* __restrict__ ce_g,
                          float* __restrict__ out_aux, int N) {
  const int e = threadIdx.x;  // 64
  float v = (pi_g[e] / (float)N) * (ce_g[e] / ((float)N * 8.0f)) * 64.0f * 0.01f;
#pragma unroll
  for (int off = 32; off; off >>= 1) v += __shfl_down(v, off, 64);
  if (e == 0) *out_aux = v;
}

extern "C" void kernel_launch(void* const* d_in, const int* in_sizes, int n_in,
                              void* d_out, int out_size, void* d_ws, size_t ws_size,
                              hipStream_t stream) {
  (void)n_in; (void)out_size; (void)ws_size;
  const float* x = (const float*)d_in[0];
  const float* w = (const float*)d_in[1];
  float* out = (float*)d_out;
  const int N = in_sizes[0] / DDIM;  // 16384

  ushort* wf = (ushort*)d_ws;  // 128*12*512 ushorts = 1.5 MiB
  float* pi_g = (float*)((char*)d_ws + (size_t)128 * 12 * 512 * 2);
  float* ce_g = pi_g + 64;

  hipMemsetAsync(pi_g, 0, 128 * sizeof(float), stream);
  build_wfrag<<<128, 256, 0, stream>>>(w, wf);
  moe_gate_main<<<N / 64, 1024, 0, stream>>>(x, wf, out, pi_g, ce_g, N);
  aux_final<<<1, 64, 0, stream>>>(pi_g, ce_g, out + (size_t)N * 16, N);
}

// Round 9
// 127.341 us; speedup vs baseline: 1.2954x; 1.2954x over previous
//
#include <hip/hip_runtime.h>
#include <math.h>

#define DDIM 4096
#define TPB 32    // tokens per block
#define NSTEP 64  // K steps of 64

// LDS byte layout: x dbuf 2x8704 (8 chunks x 1088B), w dbuf 2x24576
#define XBUFSZ 8704
#define WBUF0 17408
#define WBUFSZ 24576
#define SMEM_FLOATS 16640  // 66560 B total

typedef short s16x8 __attribute__((ext_vector_type(8)));
typedef float f32x4 __attribute__((ext_vector_type(4)));

__device__ __forceinline__ unsigned cvt_pk_bf16(float a, float b) {
  unsigned r;
  asm("v_cvt_pk_bf16_f32 %0, %1, %2" : "=v"(r) : "v"(a), "v"(b));
  return r;  // lo16 = bf16(a), hi16 = bf16(b)
}

// 3-way bf16 split of two floats -> packed hi/mid/lo words
__device__ __forceinline__ void split2(float a, float b, unsigned& H,
                                       unsigned& M, unsigned& L) {
  H = cvt_pk_bf16(a, b);
  float h0 = __uint_as_float(H << 16);
  float h1 = __uint_as_float(H & 0xffff0000u);
  float r0 = a - h0, r1 = b - h1;
  M = cvt_pk_bf16(r0, r1);
  float m0 = __uint_as_float(M << 16);
  float m1 = __uint_as_float(M & 0xffff0000u);
  L = cvt_pk_bf16(r0 - m0, r1 - m1);
}

union U8 { unsigned u[4]; s16x8 v; };
__device__ __forceinline__ s16x8 pack8(const unsigned* a) {
  U8 t;
  t.u[0] = a[0]; t.u[1] = a[1]; t.u[2] = a[2]; t.u[3] = a[3];
  return t.v;
}

#define MFMA(A, B, C) __builtin_amdgcn_mfma_f32_16x16x32_bf16(A, B, C, 0, 0, 0)

// stage one 64-k step: x 8x1KB chunks (4 tokens each, XOR-source-swizzled,
// 1088B LDS stride) + w 24x1KB fragments. 8 DMA issues per wave.
__device__ __forceinline__ void stage_step(const float* __restrict__ x,
                                           const ushort* __restrict__ wf,
                                           char* smem, int buf, int ks,
                                           int tok0, int wv, int lane) {
  char* xb = smem + buf * XBUFSZ;
#pragma unroll
  for (int j = 0; j < 2; ++j) {
    const int c = wv * 2 + j;  // chunk 0..7 -> tokens 4c..4c+3
    const float* src = x + (size_t)(tok0 + c * 4 + (lane >> 4)) * DDIM +
                       ks * 64 + (((lane & 15) ^ (lane >> 4)) << 2);
    __builtin_amdgcn_global_load_lds(
        (const __attribute__((address_space(1))) void*)src,
        (__attribute__((address_space(3))) void*)(xb + c * 1088), 16, 0, 0);
  }
  char* wb = smem + WBUF0 + buf * WBUFSZ;
#pragma unroll
  for (int j = 0; j < 6; ++j) {
    const int f = wv * 6 + j;  // 0..23
    const int kt = f >= 12 ? 1 : 0;
    const int c = f - kt * 12;
    const ushort* src = wf + ((size_t)(ks * 2 + kt) * 12 + c) * 512 + lane * 8;
    __builtin_amdgcn_global_load_lds(
        (const __attribute__((address_space(1))) void*)src,
        (__attribute__((address_space(3))) void*)(wb + kt * 12288 + c * 1024),
        16, 0, 0);
  }
}

// consume one staged 64-k step: 2 k-tiles x (x-split + 2 expert-subtiles)
__device__ __forceinline__ void compute_step(const char* smem, int buf, int tg,
                                             int ep, int lane, f32x4 accH[2],
                                             f32x4 accC[2]) {
  const char* xb = smem + buf * XBUFSZ;
  const char* wb = smem + WBUF0 + buf * WBUFSZ;
  const int c = (tg * 16 + (lane & 15)) >> 2;  // x chunk
  const int r = lane & 3;                      // row within chunk
#pragma unroll
  for (int kt = 0; kt < 2; ++kt) {
    const int s0 = kt * 8 + (lane >> 4) * 2;
    const f32x4 xa = *(const f32x4*)(xb + c * 1088 + r * 256 + ((s0 ^ r) << 4));
    const f32x4 xv =
        *(const f32x4*)(xb + c * 1088 + r * 256 + (((s0 + 1) ^ r) << 4));
    unsigned AH[4], AM[4], AL[4];
    split2(xa[0], xa[1], AH[0], AM[0], AL[0]);
    split2(xa[2], xa[3], AH[1], AM[1], AL[1]);
    split2(xv[0], xv[1], AH[2], AM[2], AL[2]);
    split2(xv[2], xv[3], AH[3], AM[3], AL[3]);
    const s16x8 ah = pack8(AH), am = pack8(AM), al = pack8(AL);
    const char* wk = wb + kt * 12288 + ep * 6144 + lane * 16;
#pragma unroll
    for (int sub = 0; sub < 2; ++sub) {
      const s16x8 bh = *(const s16x8*)(wk + (sub * 3 + 0) * 1024);
      const s16x8 bm = *(const s16x8*)(wk + (sub * 3 + 1) * 1024);
      const s16x8 bl = *(const s16x8*)(wk + (sub * 3 + 2) * 1024);
      accH[sub] = MFMA(ah, bh, accH[sub]);
      accC[sub] = MFMA(ah, bm, accC[sub]);
      accC[sub] = MFMA(am, bh, accC[sub]);
      accC[sub] = MFMA(am, bm, accC[sub]);
      accC[sub] = MFMA(ah, bl, accC[sub]);
      accC[sub] = MFMA(al, bh, accC[sub]);
    }
  }
}

// 512 blocks x 256 thr (2 blocks/CU). Block: 32 tokens x 64 experts.
// Wave (tg = wv>>1, ep = wv&1): 16 tokens x 32 experts.
// ALL k-loop global traffic via global_load_lds + counted vmcnt + raw
// s_barrier (m97 structure) -- no per-lane VMEM the compiler can serialize.
__global__ __launch_bounds__(256, 2) void moe_gate_main(
    const float* __restrict__ x,    // [N][4096]
    const ushort* __restrict__ wf,  // [128kb][12c][512] bf16 bits
    float* __restrict__ out,        // idx [N*8], w [N*8], aux
    float* __restrict__ pi_g, float* __restrict__ ce_g, int N) {
  __shared__ float smemf[SMEM_FLOATS];
  char* smem = (char*)smemf;
  float* lt = smemf;                     // epilogue: [64 e][stride 33]
  float* inv_s = smemf + 64 * 33;        // [32]
  float* ce_lds = smemf + 64 * 33 + 32;  // [64]

  const int tid = threadIdx.x;
  const int lane = tid & 63;
  const int wv = tid >> 6;  // 0..3
  const int tg = wv >> 1;   // token half
  const int ep = wv & 1;    // expert half
  const int tok0 = blockIdx.x * TPB;

  f32x4 accH[2], accC[2];
#pragma unroll
  for (int s = 0; s < 2; ++s)
#pragma unroll
    for (int r = 0; r < 4; ++r) { accH[s][r] = 0.f; accC[s][r] = 0.f; }

  stage_step(x, wf, smem, 0, 0, tok0, wv, lane);

#pragma unroll 1
  for (int i = 0; i < NSTEP - 1; ++i) {
    stage_step(x, wf, smem, (i + 1) & 1, i + 1, tok0, wv, lane);
    asm volatile("s_waitcnt vmcnt(8)" ::: "memory");
    __builtin_amdgcn_s_barrier();
    compute_step(smem, i & 1, tg, ep, lane, accH, accC);
    __builtin_amdgcn_s_barrier();
  }
  asm volatile("s_waitcnt vmcnt(0)" ::: "memory");
  __builtin_amdgcn_s_barrier();
  compute_step(smem, (NSTEP - 1) & 1, tg, ep, lane, accH, accC);
  __syncthreads();  // release x/w LDS for epilogue reuse

  // logits -> lt[e*33 + t], unscale by 1/64 (w pre-scaled x64)
#pragma unroll
  for (int sub = 0; sub < 2; ++sub) {
    const int e = ep * 32 + sub * 16 + (lane & 15);
#pragma unroll
    for (int r = 0; r < 4; ++r) {
      const int t = tg * 16 + (lane >> 4) * 4 + r;
      lt[e * 33 + t] = (accH[sub][r] + accC[sub][r]) * 0.015625f;
    }
  }
  if (tid < 64) ce_lds[tid] = 0.f;
  __syncthreads();

  // softmax per token (store p = exp(l-m) back)
  if (tid < 32) {
    const int t = tid;
    float m = -1e30f;
#pragma unroll 1
    for (int e = 0; e < 64; ++e) m = fmaxf(m, lt[e * 33 + t]);
    float ssum = 0.f;
#pragma unroll 1
    for (int e = 0; e < 64; ++e) {
      float p = expf(lt[e * 33 + t] - m);
      lt[e * 33 + t] = p;
      ssum += p;
    }
    inv_s[t] = 1.f / ssum;
  }
  __syncthreads();

  // pi partial: per-expert sum of scores
  if (tid < 64) {
    const int e = tid;
    float ssum = 0.f;
#pragma unroll 1
    for (int t = 0; t < 32; ++t) ssum += lt[e * 33 + t] * inv_s[t];
    atomicAdd(pi_g + e, ssum);
  }
  __syncthreads();

  // stable top-8 (strict > keeps lowest index on ties; descending)
  if (tid < 32) {
    const int t = tid;
    const float invv = inv_s[t];
    const size_t tg2 = (size_t)(tok0 + t);
#pragma unroll 1
    for (int r = 0; r < 8; ++r) {
      float bv = -1.f;
      int bi = 0;
#pragma unroll 1
      for (int e = 0; e < 64; ++e) {
        float p = lt[e * 33 + t];
        if (p > bv) { bv = p; bi = e; }
      }
      lt[bi * 33 + t] = -1.f;
      atomicAdd(ce_lds + bi, 1.f);
      out[tg2 * 8 + r] = (float)bi;
      out[(size_t)N * 8 + tg2 * 8 + r] = bv * invv;
    }
  }
  __syncthreads();
  if (tid < 64) atomicAdd(ce_g + tid, ce_lds[tid]);
}

// w [64][4096] -> fragment-ordered 3-way split blob, scaled by 64
__global__ void build_wfrag(const float* __restrict__ w,
                            ushort* __restrict__ wf) {
  const int kb = blockIdx.x;  // 0..127
  const int t = threadIdx.x;  // 256
  const int eg = t >> 6, lane = t & 63;
  const int e = (eg << 4) + (lane & 15);
  const int k0 = (kb << 5) + ((lane >> 4) << 3);
  const float* src = w + (size_t)e * DDIM + k0;
  unsigned H[4], M[4], L[4];
#pragma unroll
  for (int i = 0; i < 4; ++i) {
    float a = src[2 * i] * 64.f, b = src[2 * i + 1] * 64.f;
    split2(a, b, H[i], M[i], L[i]);
  }
  const size_t base = ((size_t)kb * 12 + eg * 3) * 512 + (size_t)lane * 8;
  *(uint4*)(wf + base) = make_uint4(H[0], H[1], H[2], H[3]);
  *(uint4*)(wf + base + 512) = make_uint4(M[0], M[1], M[2], M[3]);
  *(uint4*)(wf + base + 1024) = make_uint4(L[0], L[1], L[2], L[3]);
}

__global__ void aux_final(const float* __restrict__ pi_g,
                          const float* __restrict__ ce_g,
                          float* __restrict__ out_aux, int N) {
  const int e = threadIdx.x;  // 64
  float v = (pi_g[e] / (float)N) * (ce_g[e] / ((float)N * 8.0f)) * 64.0f * 0.01f;
#pragma unroll
  for (int off = 32; off; off >>= 1) v += __shfl_down(v, off, 64);
  if (e == 0) *out_aux = v;
}

extern "C" void kernel_launch(void* const* d_in, const int* in_sizes, int n_in,
                              void* d_out, int out_size, void* d_ws,
                              size_t ws_size, hipStream_t stream) {
  (void)n_in; (void)out_size; (void)ws_size;
  const float* x = (const float*)d_in[0];
  const float* w = (const float*)d_in[1];
  float* out = (float*)d_out;
  const int N = in_sizes[0] / DDIM;  // 16384

  ushort* wf = (ushort*)d_ws;  // 128*12*512 ushorts = 1.5 MiB
  float* pi_g = (float*)((char*)d_ws + (size_t)128 * 12 * 512 * 2);
  float* ce_g = pi_g + 64;

  hipMemsetAsync(pi_g, 0, 128 * sizeof(float), stream);
  build_wfrag<<<128, 256, 0, stream>>>(w, wf);
  moe_gate_main<<<N / TPB, 256, 0, stream>>>(x, wf, out, pi_g, ce_g, N);
  aux_final<<<1, 64, 0, stream>>>(pi_g, ce_g, out + (size_t)N * 16, N);
}